// Round 1
// baseline (212.234 us; speedup 1.0000x reference)
//
#include <hip/hip_runtime.h>
#include <hip/hip_bf16.h>

// Problem constants (B,H,S,D) = (2,8,4096,64)
#define B_   2
#define H_   8
#define S_   4096
#define D_   64
#define BH_  16
#define KVB  64
#define LDK  72   // padded row length (elems) for LDS tiles: 144B stride -> 2-way bank alias only

typedef __attribute__((ext_vector_type(8))) short short8_t;  // 8 bf16 = one MFMA A/B frag
typedef __attribute__((ext_vector_type(4))) float f32x4;     // MFMA C/D frag

__device__ __forceinline__ unsigned short f2bf(float f) {
  unsigned u = __float_as_uint(f);
  u += 0x7fffu + ((u >> 16) & 1u);   // round-to-nearest-even
  return (unsigned short)(u >> 16);
}

// out[i] = bf16(a[i] + s[i]), vectorized float4 / ushort4
__global__ void addcvt_kernel(const float* __restrict__ a, const float* __restrict__ s,
                              unsigned short* __restrict__ o, int n) {
  int i = (blockIdx.x * blockDim.x + threadIdx.x) * 4;
  if (i >= n) return;
  float4 x = *(const float4*)(a + i);
  float4 y = *(const float4*)(s + i);
  ushort4 r;
  r.x = f2bf(x.x + y.x); r.y = f2bf(x.y + y.y);
  r.z = f2bf(x.z + y.z); r.w = f2bf(x.w + y.w);
  *(ushort4*)(o + i) = r;
}

// Vt[bh][d][s] = bf16(v_a[bh][s][d] + v_s[bh][s][d]) -- tiled transpose via LDS
__global__ void vtrans_kernel(const float* __restrict__ va, const float* __restrict__ vs,
                              unsigned short* __restrict__ vt) {
  __shared__ __align__(16) unsigned short t[D_][LDK];
  int bh = blockIdx.y;
  int s0 = blockIdx.x * 64;
  int tid = threadIdx.x;
  int row16 = tid >> 4;        // 0..15
  int col4  = (tid & 15) * 4;  // 0..60
#pragma unroll
  for (int p = 0; p < 4; ++p) {
    int srow = p * 16 + row16;
    const float* pa = va + ((size_t)bh * S_ + s0 + srow) * D_ + col4;
    const float* pb = vs + ((size_t)bh * S_ + s0 + srow) * D_ + col4;
    float4 x = *(const float4*)pa;
    float4 y = *(const float4*)pb;
    t[col4 + 0][srow] = f2bf(x.x + y.x);
    t[col4 + 1][srow] = f2bf(x.y + y.y);
    t[col4 + 2][srow] = f2bf(x.z + y.z);
    t[col4 + 3][srow] = f2bf(x.w + y.w);
  }
  __syncthreads();
#pragma unroll
  for (int r = 0; r < 2; ++r) {
    int e = (r * 256 + tid) * 8;
    int d = e >> 6, sc = e & 63;
    short8_t v = *(const short8_t*)&t[d][sc];
    *(short8_t*)(vt + ((size_t)bh * D_ + d) * S_ + s0 + sc) = v;
  }
}

// Flash attention: one block = 4 waves = 64 query rows of one (b,h); KV-block 64.
__global__ __launch_bounds__(256) void attn_kernel(
    const unsigned short* __restrict__ Qb, const unsigned short* __restrict__ Kb,
    const unsigned short* __restrict__ Vt, const int* __restrict__ mask,
    float* __restrict__ out) {
  __shared__ __align__(16) unsigned short lK[KVB][LDK];     // K tile [key][d]
  __shared__ __align__(16) unsigned short lV[D_][LDK];      // V tile transposed [d][key]
  __shared__ __align__(16) unsigned short lP[4][16][LDK];   // per-wave P [q][key]

  int bh = blockIdx.y;
  int b = bh >> 3;                  // H = 8
  int qbase = blockIdx.x * 64;
  int tid = threadIdx.x;
  int wave = tid >> 6;
  int lane = tid & 63;
  int l15 = lane & 15, l4 = lane >> 4;
  const int* mb = mask + (size_t)b * S_;

  // Q fragments (row = l15, k(d) = 8*l4 + j), two K=32 steps over D=64
  const unsigned short* qptr = Qb + ((size_t)bh * S_ + qbase + wave * 16 + l15) * D_ + l4 * 8;
  short8_t qf0 = *(const short8_t*)qptr;
  short8_t qf1 = *(const short8_t*)(qptr + 32);

  f32x4 accO[4];                    // output acc: 4 d-subtiles x (4 rows per lane)
  float mrow[4], lrow[4];           // per-lane rows: q = l4*4 + reg
#pragma unroll
  for (int i = 0; i < 4; ++i) { accO[i] = (f32x4)(0.0f); mrow[i] = -1e30f; lrow[i] = 0.0f; }

  for (int kv = 0; kv < S_; kv += KVB) {
    __syncthreads();
    // stage K tile (contiguous 8KB) and Vt tile
    {
      const unsigned short* gk = Kb + ((size_t)bh * S_ + kv) * D_;
#pragma unroll
      for (int r = 0; r < 2; ++r) {
        int e = (r * 256 + tid) * 8;
        int row = e >> 6, col = e & 63;
        *(short8_t*)&lK[row][col] = *(const short8_t*)(gk + e);
      }
#pragma unroll
      for (int r = 0; r < 2; ++r) {
        int e = (r * 256 + tid) * 8;
        int d = e >> 6, col = e & 63;
        *(short8_t*)&lV[d][col] = *(const short8_t*)(Vt + ((size_t)bh * D_ + d) * S_ + kv + col);
      }
    }
    __syncthreads();

    // S = Q K^T  (16q x 64keys per wave), 4 key-subtiles x 2 K-steps
    f32x4 sc[4];
#pragma unroll
    for (int n = 0; n < 4; ++n) sc[n] = (f32x4)(0.0f);
#pragma unroll
    for (int n = 0; n < 4; ++n) {
      short8_t kf0 = *(const short8_t*)&lK[n * 16 + l15][l4 * 8];
      short8_t kf1 = *(const short8_t*)&lK[n * 16 + l15][32 + l4 * 8];
      sc[n] = __builtin_amdgcn_mfma_f32_16x16x32_bf16(qf0, kf0, sc[n], 0, 0, 0);
      sc[n] = __builtin_amdgcn_mfma_f32_16x16x32_bf16(qf1, kf1, sc[n], 0, 0, 0);
    }

    int mk[4];
#pragma unroll
    for (int n = 0; n < 4; ++n) mk[n] = mb[kv + n * 16 + l15];

    // online softmax per row (row = l4*4 + reg), keys of this lane: n*16 + l15
#pragma unroll
    for (int reg = 0; reg < 4; ++reg) {
      float s0 = (mk[0] == 0) ? -1e9f : sc[0][reg] * 0.125f;
      float s1 = (mk[1] == 0) ? -1e9f : sc[1][reg] * 0.125f;
      float s2 = (mk[2] == 0) ? -1e9f : sc[2][reg] * 0.125f;
      float s3 = (mk[3] == 0) ? -1e9f : sc[3][reg] * 0.125f;
      float tmax = fmaxf(fmaxf(s0, s1), fmaxf(s2, s3));
      tmax = fmaxf(tmax, __shfl_xor(tmax, 1));
      tmax = fmaxf(tmax, __shfl_xor(tmax, 2));
      tmax = fmaxf(tmax, __shfl_xor(tmax, 4));
      tmax = fmaxf(tmax, __shfl_xor(tmax, 8));
      float mold = mrow[reg];
      float mnew = fmaxf(mold, tmax);
      float scale = __expf(mold - mnew);
      mrow[reg] = mnew;
      float p0 = __expf(s0 - mnew);
      float p1 = __expf(s1 - mnew);
      float p2 = __expf(s2 - mnew);
      float p3 = __expf(s3 - mnew);
      lrow[reg] = lrow[reg] * scale + ((p0 + p1) + (p2 + p3));
      accO[0][reg] *= scale; accO[1][reg] *= scale;
      accO[2][reg] *= scale; accO[3][reg] *= scale;
      int prow = l4 * 4 + reg;
      lP[wave][prow][ 0 + l15] = f2bf(p0);
      lP[wave][prow][16 + l15] = f2bf(p1);
      lP[wave][prow][32 + l15] = f2bf(p2);
      lP[wave][prow][48 + l15] = f2bf(p3);
    }

    // O += P V : A = P (row=q=l15, k=key), B = Vt (col=d=l15, k=key)
#pragma unroll
    for (int kk = 0; kk < 2; ++kk) {
      short8_t pa = *(const short8_t*)&lP[wave][l15][kk * 32 + l4 * 8];
#pragma unroll
      for (int dn = 0; dn < 4; ++dn) {
        short8_t vb = *(const short8_t*)&lV[dn * 16 + l15][kk * 32 + l4 * 8];
        accO[dn] = __builtin_amdgcn_mfma_f32_16x16x32_bf16(pa, vb, accO[dn], 0, 0, 0);
      }
    }
  }

  // finalize: reduce row-sums across the 16 lanes holding each row, then write O
  float inv[4];
#pragma unroll
  for (int reg = 0; reg < 4; ++reg) {
    float lr = lrow[reg];
    lr += __shfl_xor(lr, 1);
    lr += __shfl_xor(lr, 2);
    lr += __shfl_xor(lr, 4);
    lr += __shfl_xor(lr, 8);
    inv[reg] = 1.0f / lr;
  }
#pragma unroll
  for (int dn = 0; dn < 4; ++dn) {
#pragma unroll
    for (int reg = 0; reg < 4; ++reg) {
      int row = qbase + wave * 16 + l4 * 4 + reg;
      out[((size_t)bh * S_ + row) * D_ + dn * 16 + l15] = accO[dn][reg] * inv[reg];
    }
  }
}

extern "C" void kernel_launch(void* const* d_in, const int* in_sizes, int n_in,
                              void* d_out, int out_size, void* d_ws, size_t ws_size,
                              hipStream_t stream) {
  const float* q_a = (const float*)d_in[0];
  const float* k_a = (const float*)d_in[1];
  const float* v_a = (const float*)d_in[2];
  const float* q_s = (const float*)d_in[3];
  const float* k_s = (const float*)d_in[4];
  const float* v_s = (const float*)d_in[5];
  const int*   mask = (const int*)d_in[6];
  float* out = (float*)d_out;

  const int N = BH_ * S_ * D_;  // 4,194,304 per tensor
  unsigned short* qb = (unsigned short*)d_ws;
  unsigned short* kb = qb + N;
  unsigned short* vt = kb + N;
  (void)ws_size; (void)in_sizes; (void)n_in; (void)out_size;

  // prepass: fold type sums into bf16; V transposed per head
  addcvt_kernel<<<N / (256 * 4), 256, 0, stream>>>(q_a, q_s, qb, N);
  addcvt_kernel<<<N / (256 * 4), 256, 0, stream>>>(k_a, k_s, kb, N);
  {
    dim3 g(S_ / 64, BH_);
    vtrans_kernel<<<g, 256, 0, stream>>>(v_a, v_s, vt);
  }
  // flash attention
  {
    dim3 g(S_ / 64, BH_);
    attn_kernel<<<g, 256, 0, stream>>>(qb, kb, vt, mask, out);
  }
}